// Round 1
// baseline (2828.464 us; speedup 1.0000x reference)
//
#include <hip/hip_runtime.h>

// GIN: 2x GINConv(eps=0) on N=50000 nodes, E=800000 edges, d=128.
// Pipeline per conv: agg = scatter_add(h[src] -> dst); z = h + agg (fused into
// GEMM staging); h' = relu(relu(z@Wa+ba)@Wb+bb).
// Round 1: correctness-first fp32. Aggregation via global f32 atomics
// (102.4M/conv — expected bottleneck, CSR gather planned next).

#define NN 50000
#define NE 800000
#define FD 128

// One edge handled by 32 threads, each moving 4 consecutive floats (float4).
__global__ __launch_bounds__(256) void scatter_add_kernel(
    const float* __restrict__ h, const int* __restrict__ src,
    const int* __restrict__ dst, float* __restrict__ agg)
{
    int tid = blockIdx.x * 256 + threadIdx.x;
    int e = tid >> 5;
    if (e >= NE) return;
    int f4 = (tid & 31) << 2;
    int s = src[e];
    int d = dst[e];
    float4 v = *reinterpret_cast<const float4*>(h + (size_t)s * FD + f4);
    float* o = agg + (size_t)d * FD + f4;
    atomicAdd(o + 0, v.x);
    atomicAdd(o + 1, v.y);
    atomicAdd(o + 2, v.z);
    atomicAdd(o + 3, v.w);
}

// out[M=50000,128] = relu( (A (+B)) @ W + bias ), W is [128,128] row-major.
// Block: 64 rows x 128 cols, 256 threads, per-thread 4 rows x 8 cols
// (cols split tx*4 and tx*4+64 to keep LDS W-reads at the 2-way-free level).
template <bool ADD>
__global__ __launch_bounds__(256) void gemm_bias_relu(
    const float* __restrict__ A, const float* __restrict__ B,
    const float* __restrict__ W, const float* __restrict__ bias,
    float* __restrict__ out)
{
    __shared__ float zs[64][33];   // +1 pad: conflict-free row reads
    __shared__ float ws[32][128];

    const int tid = threadIdx.x;
    const int tx = tid & 15;       // col group
    const int ty = tid >> 4;       // row group
    const int row0 = blockIdx.x * 64;

    float acc[4][8];
#pragma unroll
    for (int i = 0; i < 4; ++i)
#pragma unroll
        for (int j = 0; j < 8; ++j) acc[i][j] = 0.f;

    // staging assignments
    const int zr = tid >> 2;            // 0..63 (row of z tile)
    const int zc = (tid & 3) * 8;       // 0,8,16,24 (col chunk of 8)
    const int wr = tid >> 3;            // 0..31 (row of W tile)
    const int wc = (tid & 7) * 16;      // 0..112 (col chunk of 16)

    int grow = row0 + zr;
    if (grow >= NN) grow = NN - 1;      // clamp: garbage rows discarded at store

    for (int k0 = 0; k0 < FD; k0 += 32) {
        // stage z (64x32), fusing z = A + B when ADD
        const float* ap = A + (size_t)grow * FD + k0 + zc;
        float4 v0 = *reinterpret_cast<const float4*>(ap);
        float4 v1 = *reinterpret_cast<const float4*>(ap + 4);
        if (ADD) {
            const float* bp = B + (size_t)grow * FD + k0 + zc;
            float4 u0 = *reinterpret_cast<const float4*>(bp);
            float4 u1 = *reinterpret_cast<const float4*>(bp + 4);
            v0.x += u0.x; v0.y += u0.y; v0.z += u0.z; v0.w += u0.w;
            v1.x += u1.x; v1.y += u1.y; v1.z += u1.z; v1.w += u1.w;
        }
        zs[zr][zc + 0] = v0.x; zs[zr][zc + 1] = v0.y;
        zs[zr][zc + 2] = v0.z; zs[zr][zc + 3] = v0.w;
        zs[zr][zc + 4] = v1.x; zs[zr][zc + 5] = v1.y;
        zs[zr][zc + 6] = v1.z; zs[zr][zc + 7] = v1.w;

        // stage W chunk (32x128)
        const float* wp = W + (size_t)(k0 + wr) * FD + wc;
        float4 w0 = *reinterpret_cast<const float4*>(wp + 0);
        float4 w1 = *reinterpret_cast<const float4*>(wp + 4);
        float4 w2 = *reinterpret_cast<const float4*>(wp + 8);
        float4 w3 = *reinterpret_cast<const float4*>(wp + 12);
        *reinterpret_cast<float4*>(&ws[wr][wc + 0])  = w0;
        *reinterpret_cast<float4*>(&ws[wr][wc + 4])  = w1;
        *reinterpret_cast<float4*>(&ws[wr][wc + 8])  = w2;
        *reinterpret_cast<float4*>(&ws[wr][wc + 12]) = w3;

        __syncthreads();

#pragma unroll
        for (int k = 0; k < 32; ++k) {
            float4 wa = *reinterpret_cast<const float4*>(&ws[k][tx * 4]);
            float4 wb = *reinterpret_cast<const float4*>(&ws[k][tx * 4 + 64]);
            float z0 = zs[ty * 4 + 0][k];
            float z1 = zs[ty * 4 + 1][k];
            float z2 = zs[ty * 4 + 2][k];
            float z3 = zs[ty * 4 + 3][k];
            acc[0][0] = fmaf(z0, wa.x, acc[0][0]);
            acc[0][1] = fmaf(z0, wa.y, acc[0][1]);
            acc[0][2] = fmaf(z0, wa.z, acc[0][2]);
            acc[0][3] = fmaf(z0, wa.w, acc[0][3]);
            acc[0][4] = fmaf(z0, wb.x, acc[0][4]);
            acc[0][5] = fmaf(z0, wb.y, acc[0][5]);
            acc[0][6] = fmaf(z0, wb.z, acc[0][6]);
            acc[0][7] = fmaf(z0, wb.w, acc[0][7]);
            acc[1][0] = fmaf(z1, wa.x, acc[1][0]);
            acc[1][1] = fmaf(z1, wa.y, acc[1][1]);
            acc[1][2] = fmaf(z1, wa.z, acc[1][2]);
            acc[1][3] = fmaf(z1, wa.w, acc[1][3]);
            acc[1][4] = fmaf(z1, wb.x, acc[1][4]);
            acc[1][5] = fmaf(z1, wb.y, acc[1][5]);
            acc[1][6] = fmaf(z1, wb.z, acc[1][6]);
            acc[1][7] = fmaf(z1, wb.w, acc[1][7]);
            acc[2][0] = fmaf(z2, wa.x, acc[2][0]);
            acc[2][1] = fmaf(z2, wa.y, acc[2][1]);
            acc[2][2] = fmaf(z2, wa.z, acc[2][2]);
            acc[2][3] = fmaf(z2, wa.w, acc[2][3]);
            acc[2][4] = fmaf(z2, wb.x, acc[2][4]);
            acc[2][5] = fmaf(z2, wb.y, acc[2][5]);
            acc[2][6] = fmaf(z2, wb.z, acc[2][6]);
            acc[2][7] = fmaf(z2, wb.w, acc[2][7]);
            acc[3][0] = fmaf(z3, wa.x, acc[3][0]);
            acc[3][1] = fmaf(z3, wa.y, acc[3][1]);
            acc[3][2] = fmaf(z3, wa.z, acc[3][2]);
            acc[3][3] = fmaf(z3, wa.w, acc[3][3]);
            acc[3][4] = fmaf(z3, wb.x, acc[3][4]);
            acc[3][5] = fmaf(z3, wb.y, acc[3][5]);
            acc[3][6] = fmaf(z3, wb.z, acc[3][6]);
            acc[3][7] = fmaf(z3, wb.w, acc[3][7]);
        }
        __syncthreads();
    }

    // epilogue: bias + relu, cols {tx*4..+3} and {tx*4+64..+3}
    float bv[8];
#pragma unroll
    for (int j = 0; j < 4; ++j) {
        bv[j]     = bias[tx * 4 + j];
        bv[j + 4] = bias[tx * 4 + 64 + j];
    }
#pragma unroll
    for (int i = 0; i < 4; ++i) {
        int r = row0 + ty * 4 + i;
        if (r < NN) {
            float4 o0, o1;
            o0.x = fmaxf(acc[i][0] + bv[0], 0.f);
            o0.y = fmaxf(acc[i][1] + bv[1], 0.f);
            o0.z = fmaxf(acc[i][2] + bv[2], 0.f);
            o0.w = fmaxf(acc[i][3] + bv[3], 0.f);
            o1.x = fmaxf(acc[i][4] + bv[4], 0.f);
            o1.y = fmaxf(acc[i][5] + bv[5], 0.f);
            o1.z = fmaxf(acc[i][6] + bv[6], 0.f);
            o1.w = fmaxf(acc[i][7] + bv[7], 0.f);
            *reinterpret_cast<float4*>(out + (size_t)r * FD + tx * 4)      = o0;
            *reinterpret_cast<float4*>(out + (size_t)r * FD + tx * 4 + 64) = o1;
        }
    }
}

extern "C" void kernel_launch(void* const* d_in, const int* in_sizes, int n_in,
                              void* d_out, int out_size, void* d_ws, size_t ws_size,
                              hipStream_t stream) {
    const float* x   = (const float*)d_in[0];
    const int*   ei  = (const int*)d_in[1];
    const int*   src = ei;          // edge_index[0]
    const int*   dst = ei + NE;     // edge_index[1]
    const float* W1a = (const float*)d_in[2];
    const float* b1a = (const float*)d_in[3];
    const float* W1b = (const float*)d_in[4];
    const float* b1b = (const float*)d_in[5];
    const float* W2a = (const float*)d_in[6];
    const float* b2a = (const float*)d_in[7];
    const float* W2b = (const float*)d_in[8];
    const float* b2b = (const float*)d_in[9];

    float* out  = (float*)d_out;
    float* buf0 = (float*)d_ws;                 // 25.6 MB
    float* buf1 = buf0 + (size_t)NN * FD;       // 25.6 MB  (needs ws >= 51.2 MB)

    const size_t featBytes = (size_t)NN * FD * sizeof(float);
    const int scatterBlocks = (NE * 32) / 256;  // 100000
    const int gemmBlocks = (NN + 63) / 64;      // 782

    // ---- conv1 ----
    hipMemsetAsync(buf0, 0, featBytes, stream);
    scatter_add_kernel<<<scatterBlocks, 256, 0, stream>>>(x, src, dst, buf0);
    // buf1 = relu((x+agg) @ W1a + b1a)
    gemm_bias_relu<true><<<gemmBlocks, 256, 0, stream>>>(buf0, x, W1a, b1a, buf1);
    // out(h) = relu(buf1 @ W1b + b1b)   (post-conv relu is a no-op)
    gemm_bias_relu<false><<<gemmBlocks, 256, 0, stream>>>(buf1, nullptr, W1b, b1b, out);

    // ---- conv2 ----
    hipMemsetAsync(buf1, 0, featBytes, stream);
    scatter_add_kernel<<<scatterBlocks, 256, 0, stream>>>(out, src, dst, buf1);
    gemm_bias_relu<true><<<gemmBlocks, 256, 0, stream>>>(buf1, out, W2a, b2a, buf0);
    gemm_bias_relu<false><<<gemmBlocks, 256, 0, stream>>>(buf0, nullptr, W2b, b2b, out);
}

// Round 2
// 390.398 us; speedup vs baseline: 7.2451x; 7.2451x over previous
//
#include <hip/hip_runtime.h>

// GIN: 2x GINConv(eps=0), N=50000 nodes, E=800000 edges, d=128.
// R2: replace 204.8M-f32-atomic scatter with per-call CSR build (1.6M int
// atomics) + gather-sum. z = h + sum_{j->i} h_j fused into gather epilogue.
// CSR built once, reused by both convs.
//
// ws layout: [ zbuf 25.6MB | row_off (NN+1) | cursor (NN) | deg (NN) | csr_src (NE) ]

#define NN 50000
#define NE 800000
#define FD 128

// ---------------- CSR build ----------------

__global__ __launch_bounds__(256) void hist_kernel(
    const int* __restrict__ dst, int* __restrict__ deg)
{
    int e = blockIdx.x * 256 + threadIdx.x;
    if (e < NE) atomicAdd(&deg[dst[e]], 1);
}

// single-block exclusive scan of deg[0..NN) -> off[0..NN]
__global__ __launch_bounds__(1024) void scan_kernel(
    const int* __restrict__ deg, int* __restrict__ off)
{
    __shared__ int wsum[16];
    __shared__ int woff[16];
    __shared__ int carry;
    const int tid = threadIdx.x, lane = tid & 63, w = tid >> 6;
    if (tid == 0) carry = 0;
    __syncthreads();
    for (int base = 0; base <= NN; base += 1024) {
        int i = base + tid;
        int v = (i < NN) ? deg[i] : 0;
        int sc = v;                      // wave inclusive scan
#pragma unroll
        for (int s = 1; s < 64; s <<= 1) {
            int t = __shfl_up(sc, s);
            if (lane >= s) sc += t;
        }
        if (lane == 63) wsum[w] = sc;
        __syncthreads();
        if (w == 0) {
            int t = (lane < 16) ? wsum[lane] : 0;
            int ts = t;
#pragma unroll
            for (int s = 1; s < 64; s <<= 1) {
                int u = __shfl_up(ts, s);
                if (lane >= s) ts += u;
            }
            if (lane < 16) woff[lane] = carry + ts - t;
            if (lane == 15) carry += ts;     // lockstep: reads above done first
        }
        __syncthreads();
        if (i <= NN) off[i] = woff[w] + sc - v;
        __syncthreads();                 // protect wsum for next chunk
    }
}

__global__ __launch_bounds__(256) void fill_kernel(
    const int* __restrict__ src, const int* __restrict__ dst,
    int* __restrict__ cursor, int* __restrict__ csr_src)
{
    int e = blockIdx.x * 256 + threadIdx.x;
    if (e < NE) {
        int pos = atomicAdd(&cursor[dst[e]], 1);
        csr_src[pos] = src[e];
    }
}

// ---------------- gather-sum:  z[i] = h[i] + sum_{e in row i} h[csr_src[e]] --
// one wave per node; lane owns 2 floats (float2), 64 lanes cover the 128-row.

__global__ __launch_bounds__(256) void gather_sum_kernel(
    const float* __restrict__ h, const int* __restrict__ csr_src,
    const int* __restrict__ row_off, float* __restrict__ z)
{
    const int node = blockIdx.x * 4 + (threadIdx.x >> 6);
    const int lane = threadIdx.x & 63;
    if (node >= NN) return;

    const int beg = row_off[node];
    const int end = row_off[node + 1];

    float2 acc = *reinterpret_cast<const float2*>(h + (size_t)node * FD + lane * 2);

    for (int e0 = beg; e0 < end; e0 += 64) {
        int n = end - e0; if (n > 64) n = 64;
        int sidx = (lane < n) ? csr_src[e0 + lane] : 0;
        for (int j = 0; j < n; ++j) {
            int s = __shfl(sidx, j);
            float2 v = *reinterpret_cast<const float2*>(h + (size_t)s * FD + lane * 2);
            acc.x += v.x;
            acc.y += v.y;
        }
    }
    *reinterpret_cast<float2*>(z + (size_t)node * FD + lane * 2) = acc;
}

// ---------------- GEMM: out = relu(A @ W + bias),  W row-major [128,128] ----

__global__ __launch_bounds__(256) void gemm_bias_relu(
    const float* __restrict__ A, const float* __restrict__ W,
    const float* __restrict__ bias, float* __restrict__ out)
{
    __shared__ float zs[64][33];   // +1 pad: conflict-free row reads
    __shared__ float ws[32][128];

    const int tid = threadIdx.x;
    const int tx = tid & 15;       // col group
    const int ty = tid >> 4;       // row group
    const int row0 = blockIdx.x * 64;

    float acc[4][8];
#pragma unroll
    for (int i = 0; i < 4; ++i)
#pragma unroll
        for (int j = 0; j < 8; ++j) acc[i][j] = 0.f;

    const int zr = tid >> 2;            // 0..63
    const int zc = (tid & 3) * 8;       // 0,8,16,24
    const int wr = tid >> 3;            // 0..31
    const int wc = (tid & 7) * 16;      // 0..112

    int grow = row0 + zr;
    if (grow >= NN) grow = NN - 1;      // clamp; garbage rows discarded at store

    for (int k0 = 0; k0 < FD; k0 += 32) {
        const float* ap = A + (size_t)grow * FD + k0 + zc;
        float4 v0 = *reinterpret_cast<const float4*>(ap);
        float4 v1 = *reinterpret_cast<const float4*>(ap + 4);
        zs[zr][zc + 0] = v0.x; zs[zr][zc + 1] = v0.y;
        zs[zr][zc + 2] = v0.z; zs[zr][zc + 3] = v0.w;
        zs[zr][zc + 4] = v1.x; zs[zr][zc + 5] = v1.y;
        zs[zr][zc + 6] = v1.z; zs[zr][zc + 7] = v1.w;

        const float* wp = W + (size_t)(k0 + wr) * FD + wc;
        float4 w0 = *reinterpret_cast<const float4*>(wp + 0);
        float4 w1 = *reinterpret_cast<const float4*>(wp + 4);
        float4 w2 = *reinterpret_cast<const float4*>(wp + 8);
        float4 w3 = *reinterpret_cast<const float4*>(wp + 12);
        *reinterpret_cast<float4*>(&ws[wr][wc + 0])  = w0;
        *reinterpret_cast<float4*>(&ws[wr][wc + 4])  = w1;
        *reinterpret_cast<float4*>(&ws[wr][wc + 8])  = w2;
        *reinterpret_cast<float4*>(&ws[wr][wc + 12]) = w3;

        __syncthreads();

#pragma unroll
        for (int k = 0; k < 32; ++k) {
            float4 wa = *reinterpret_cast<const float4*>(&ws[k][tx * 4]);
            float4 wb = *reinterpret_cast<const float4*>(&ws[k][tx * 4 + 64]);
            float z0 = zs[ty * 4 + 0][k];
            float z1 = zs[ty * 4 + 1][k];
            float z2 = zs[ty * 4 + 2][k];
            float z3 = zs[ty * 4 + 3][k];
            acc[0][0] = fmaf(z0, wa.x, acc[0][0]);
            acc[0][1] = fmaf(z0, wa.y, acc[0][1]);
            acc[0][2] = fmaf(z0, wa.z, acc[0][2]);
            acc[0][3] = fmaf(z0, wa.w, acc[0][3]);
            acc[0][4] = fmaf(z0, wb.x, acc[0][4]);
            acc[0][5] = fmaf(z0, wb.y, acc[0][5]);
            acc[0][6] = fmaf(z0, wb.z, acc[0][6]);
            acc[0][7] = fmaf(z0, wb.w, acc[0][7]);
            acc[1][0] = fmaf(z1, wa.x, acc[1][0]);
            acc[1][1] = fmaf(z1, wa.y, acc[1][1]);
            acc[1][2] = fmaf(z1, wa.z, acc[1][2]);
            acc[1][3] = fmaf(z1, wa.w, acc[1][3]);
            acc[1][4] = fmaf(z1, wb.x, acc[1][4]);
            acc[1][5] = fmaf(z1, wb.y, acc[1][5]);
            acc[1][6] = fmaf(z1, wb.z, acc[1][6]);
            acc[1][7] = fmaf(z1, wb.w, acc[1][7]);
            acc[2][0] = fmaf(z2, wa.x, acc[2][0]);
            acc[2][1] = fmaf(z2, wa.y, acc[2][1]);
            acc[2][2] = fmaf(z2, wa.z, acc[2][2]);
            acc[2][3] = fmaf(z2, wa.w, acc[2][3]);
            acc[2][4] = fmaf(z2, wb.x, acc[2][4]);
            acc[2][5] = fmaf(z2, wb.y, acc[2][5]);
            acc[2][6] = fmaf(z2, wb.z, acc[2][6]);
            acc[2][7] = fmaf(z2, wb.w, acc[2][7]);
            acc[3][0] = fmaf(z3, wa.x, acc[3][0]);
            acc[3][1] = fmaf(z3, wa.y, acc[3][1]);
            acc[3][2] = fmaf(z3, wa.z, acc[3][2]);
            acc[3][3] = fmaf(z3, wa.w, acc[3][3]);
            acc[3][4] = fmaf(z3, wb.x, acc[3][4]);
            acc[3][5] = fmaf(z3, wb.y, acc[3][5]);
            acc[3][6] = fmaf(z3, wb.z, acc[3][6]);
            acc[3][7] = fmaf(z3, wb.w, acc[3][7]);
        }
        __syncthreads();
    }

    float bv[8];
#pragma unroll
    for (int j = 0; j < 4; ++j) {
        bv[j]     = bias[tx * 4 + j];
        bv[j + 4] = bias[tx * 4 + 64 + j];
    }
#pragma unroll
    for (int i = 0; i < 4; ++i) {
        int r = row0 + ty * 4 + i;
        if (r < NN) {
            float4 o0, o1;
            o0.x = fmaxf(acc[i][0] + bv[0], 0.f);
            o0.y = fmaxf(acc[i][1] + bv[1], 0.f);
            o0.z = fmaxf(acc[i][2] + bv[2], 0.f);
            o0.w = fmaxf(acc[i][3] + bv[3], 0.f);
            o1.x = fmaxf(acc[i][4] + bv[4], 0.f);
            o1.y = fmaxf(acc[i][5] + bv[5], 0.f);
            o1.z = fmaxf(acc[i][6] + bv[6], 0.f);
            o1.w = fmaxf(acc[i][7] + bv[7], 0.f);
            *reinterpret_cast<float4*>(out + (size_t)r * FD + tx * 4)      = o0;
            *reinterpret_cast<float4*>(out + (size_t)r * FD + tx * 4 + 64) = o1;
        }
    }
}

extern "C" void kernel_launch(void* const* d_in, const int* in_sizes, int n_in,
                              void* d_out, int out_size, void* d_ws, size_t ws_size,
                              hipStream_t stream) {
    const float* x   = (const float*)d_in[0];
    const int*   ei  = (const int*)d_in[1];
    const int*   src = ei;          // edge_index[0]
    const int*   dst = ei + NE;     // edge_index[1]
    const float* W1a = (const float*)d_in[2];
    const float* b1a = (const float*)d_in[3];
    const float* W1b = (const float*)d_in[4];
    const float* b1b = (const float*)d_in[5];
    const float* W2a = (const float*)d_in[6];
    const float* b2a = (const float*)d_in[7];
    const float* W2b = (const float*)d_in[8];
    const float* b2b = (const float*)d_in[9];

    float* out  = (float*)d_out;                    // 25.6 MB, doubles as ping-pong
    float* zbuf = (float*)d_ws;                     // 25.6 MB
    int*   row_off = (int*)(zbuf + (size_t)NN * FD);// NN+1
    int*   cursor  = row_off + (NN + 1);            // NN
    int*   deg     = cursor + NN;                   // NN
    int*   csr_src = deg + NN;                      // NE

    const int eBlocks = (NE + 255) / 256;           // 3125
    const int gBlocks = (NN + 3) / 4;               // 12500
    const int mBlocks = (NN + 63) / 64;             // 782

    // ---- CSR build (once, reused by both convs) ----
    hipMemsetAsync(deg, 0, NN * sizeof(int), stream);
    hist_kernel<<<eBlocks, 256, 0, stream>>>(dst, deg);
    scan_kernel<<<1, 1024, 0, stream>>>(deg, row_off);
    hipMemcpyAsync(cursor, row_off, NN * sizeof(int), hipMemcpyDeviceToDevice, stream);
    fill_kernel<<<eBlocks, 256, 0, stream>>>(src, dst, cursor, csr_src);

    // ---- conv1 ----
    gather_sum_kernel<<<gBlocks, 256, 0, stream>>>(x, csr_src, row_off, zbuf);
    gemm_bias_relu<<<mBlocks, 256, 0, stream>>>(zbuf, W1a, b1a, out);   // t1
    gemm_bias_relu<<<mBlocks, 256, 0, stream>>>(out, W1b, b1b, zbuf);   // h -> zbuf

    // ---- conv2 ----
    gather_sum_kernel<<<gBlocks, 256, 0, stream>>>(zbuf, csr_src, row_off, out); // z2
    gemm_bias_relu<<<mBlocks, 256, 0, stream>>>(out, W2a, b2a, zbuf);   // t2
    gemm_bias_relu<<<mBlocks, 256, 0, stream>>>(zbuf, W2b, b2b, out);   // final
}

// Round 3
// 250.567 us; speedup vs baseline: 11.2882x; 1.5581x over previous
//
#include <hip/hip_runtime.h>

// GIN: 2x GINConv(eps=0), N=50000, E=800000, d=128.
// R3: bf16 everywhere (fp32 accum). Gather traffic halves; GEMMs use
// mfma_f32_16x16x32_bf16. CSR via hierarchical 3-kernel scan (was 1-block serial).
// ws: [ xb 12.8M | zb 12.8M | tb 12.8M | wt 128K | row_off | cursor | deg | bsum | boff | csr_src ]

#define NN 50000
#define NE 800000
#define FD 128
#define NBLK 196   // ceil((NN+1)/256)

typedef unsigned short u16;
typedef unsigned int u32;
typedef __attribute__((ext_vector_type(8))) short bf16x8;
typedef __attribute__((ext_vector_type(4))) float f32x4;

static __device__ __forceinline__ float b2f(u16 u) {
    return __uint_as_float(((u32)u) << 16);
}
static __device__ __forceinline__ u16 f2b(float f) {
    u32 x = __float_as_uint(f);
    u32 r = x + 0x7FFFu + ((x >> 16) & 1u);   // RNE
    return (u16)(r >> 16);
}

// ---------------- converts ----------------

__global__ __launch_bounds__(256) void convert_x_kernel(
    const float* __restrict__ x, u16* __restrict__ xb)
{
    int gid = blockIdx.x * 256 + threadIdx.x;     // 3125*256 threads, 8 elems each
    size_t base = (size_t)gid * 8;
    float4 a = *reinterpret_cast<const float4*>(x + base);
    float4 b = *reinterpret_cast<const float4*>(x + base + 4);
    u32 w0 = (u32)f2b(a.x) | ((u32)f2b(a.y) << 16);
    u32 w1 = (u32)f2b(a.z) | ((u32)f2b(a.w) << 16);
    u32 w2 = (u32)f2b(b.x) | ((u32)f2b(b.y) << 16);
    u32 w3 = (u32)f2b(b.z) | ((u32)f2b(b.w) << 16);
    uint4 o = {w0, w1, w2, w3};
    *reinterpret_cast<uint4*>(xb + base) = o;
}

// W [128][128] fp32 row-major -> WT [128][128] bf16 with WT[n][k] = W[k][n]
__global__ __launch_bounds__(256) void convert_w_kernel(
    const float* __restrict__ w0, const float* __restrict__ w1,
    const float* __restrict__ w2, const float* __restrict__ w3,
    u16* __restrict__ wt)
{
    int b = blockIdx.x;
    const float* W = (b == 0) ? w0 : (b == 1) ? w1 : (b == 2) ? w2 : w3;
    u16* out = wt + (size_t)b * FD * FD;
    for (int idx = threadIdx.x; idx < FD * FD; idx += 256) {
        int n = idx >> 7, k = idx & 127;
        out[idx] = f2b(W[k * FD + n]);
    }
}

// ---------------- CSR build ----------------

__global__ __launch_bounds__(256) void hist_kernel(
    const int* __restrict__ dst, int* __restrict__ deg)
{
    int e = blockIdx.x * 256 + threadIdx.x;
    if (e < NE) atomicAdd(&deg[dst[e]], 1);
}

// local exclusive scan of 256-chunks; bsum[b] = chunk total
__global__ __launch_bounds__(256) void scan_local_kernel(
    const int* __restrict__ deg, int* __restrict__ off, int* __restrict__ bsum)
{
    __shared__ int wsum[4];
    const int tid = threadIdx.x, lane = tid & 63, wv = tid >> 6;
    int i = blockIdx.x * 256 + tid;
    int v = (i < NN) ? deg[i] : 0;
    int sc = v;
#pragma unroll
    for (int s = 1; s < 64; s <<= 1) {
        int t = __shfl_up(sc, s);
        if (lane >= s) sc += t;
    }
    if (lane == 63) wsum[wv] = sc;
    __syncthreads();
    int woff = 0;
#pragma unroll
    for (int k = 0; k < 3; ++k)
        if (wv > k) woff += wsum[k];
    if (i <= NN) off[i] = woff + sc - v;
    if (tid == 0) bsum[blockIdx.x] = wsum[0] + wsum[1] + wsum[2] + wsum[3];
}

// exclusive scan of bsum[NBLK] -> boff
__global__ __launch_bounds__(256) void scan_block_kernel(
    const int* __restrict__ bsum, int* __restrict__ boff)
{
    __shared__ int wsum[4];
    const int tid = threadIdx.x, lane = tid & 63, wv = tid >> 6;
    int v = (tid < NBLK) ? bsum[tid] : 0;
    int sc = v;
#pragma unroll
    for (int s = 1; s < 64; s <<= 1) {
        int t = __shfl_up(sc, s);
        if (lane >= s) sc += t;
    }
    if (lane == 63) wsum[wv] = sc;
    __syncthreads();
    int woff = 0;
#pragma unroll
    for (int k = 0; k < 3; ++k)
        if (wv > k) woff += wsum[k];
    if (tid < NBLK) boff[tid] = woff + sc - v;
}

__global__ __launch_bounds__(256) void scan_add_kernel(
    int* __restrict__ off, const int* __restrict__ boff)
{
    int i = blockIdx.x * 256 + threadIdx.x;
    if (i <= NN) off[i] += boff[blockIdx.x];
}

__global__ __launch_bounds__(256) void fill_kernel(
    const int* __restrict__ src, const int* __restrict__ dst,
    int* __restrict__ cursor, int* __restrict__ csr_src)
{
    int e = blockIdx.x * 256 + threadIdx.x;
    if (e < NE) {
        int pos = atomicAdd(&cursor[dst[e]], 1);
        csr_src[pos] = src[e];
    }
}

// ---------------- gather-sum (bf16 in, bf16 out, fp32 accum) ----------------
// one wave per node; 32-lane halves process 2 edges/iter; lane owns 4 cols.

__global__ __launch_bounds__(256) void gather_sum_kernel(
    const u16* __restrict__ h, const int* __restrict__ csr_src,
    const int* __restrict__ row_off, u16* __restrict__ z)
{
    const int node = blockIdx.x * 4 + (threadIdx.x >> 6);
    const int lane = threadIdx.x & 63;
    if (node >= NN) return;
    const int half = lane >> 5;
    const int c4 = (lane & 31) * 4;

    const int beg = row_off[node];
    const int end = row_off[node + 1];

    float4 acc = {0.f, 0.f, 0.f, 0.f};
    if (half == 0) {   // self term counted once
        ushort4 s = *reinterpret_cast<const ushort4*>(h + (size_t)node * FD + c4);
        acc.x = b2f(s.x); acc.y = b2f(s.y); acc.z = b2f(s.z); acc.w = b2f(s.w);
    }

    for (int e0 = beg; e0 < end; e0 += 64) {
        int n = end - e0; if (n > 64) n = 64;
        int sidx = (lane < n) ? csr_src[e0 + lane] : 0;
        for (int j = 0; j < n; j += 2) {
            int jj = j + half;
            int s = __shfl(sidx, jj);
            if (jj < n) {
                ushort4 v = *reinterpret_cast<const ushort4*>(h + (size_t)s * FD + c4);
                acc.x += b2f(v.x); acc.y += b2f(v.y);
                acc.z += b2f(v.z); acc.w += b2f(v.w);
            }
        }
    }
    // combine halves
    acc.x += __shfl_xor(acc.x, 32);
    acc.y += __shfl_xor(acc.y, 32);
    acc.z += __shfl_xor(acc.z, 32);
    acc.w += __shfl_xor(acc.w, 32);
    if (half == 0) {
        ushort4 o = {f2b(acc.x), f2b(acc.y), f2b(acc.z), f2b(acc.w)};
        *reinterpret_cast<ushort4*>(z + (size_t)node * FD + c4) = o;
    }
}

// ---------------- MFMA GEMM: out = relu(A @ W + bias) ----------------
// A [NN][128] bf16 row-major; WT [128][128] bf16 = W^T (WT[n][k]).
// Block: 64 rows x 128 cols, 4 waves as 2Mx2N (each wave 32x64).
// k-mapping phi(g,i) = 8g+i used for BOTH A and B frags (consistency is all
// MFMA needs); D layout col=lane&15, row=(lane>>4)*4+reg  [m89-verified].

template <bool F32OUT>
__global__ __launch_bounds__(256) void gemm_mfma_kernel(
    const u16* __restrict__ A, const u16* __restrict__ WT,
    const float* __restrict__ bias, void* __restrict__ outv)
{
    __shared__ u16 a_lds[64][136];   // pad 8 bf16: row stride 272B -> 2-way banks
    __shared__ u16 w_lds[128][136];

    const int tid = threadIdx.x;
    const int lane = tid & 63;
    const int wv = tid >> 6;
    const int row0 = blockIdx.x * 64;
    const int g = lane >> 4;         // k-group
    const int l16 = lane & 15;

    // stage WT (128x128): 2048 chunks of 8 bf16
#pragma unroll
    for (int it = 0; it < 8; ++it) {
        int idx = tid + it * 256;
        int r = idx >> 4, c = (idx & 15) * 8;
        *reinterpret_cast<bf16x8*>(&w_lds[r][c]) =
            *reinterpret_cast<const bf16x8*>(WT + (size_t)r * FD + c);
    }
    // stage A tile (64x128): 1024 chunks of 8
#pragma unroll
    for (int it = 0; it < 4; ++it) {
        int idx = tid + it * 256;
        int r = idx >> 4, c = (idx & 15) * 8;
        int grow = row0 + r; if (grow >= NN) grow = NN - 1;
        *reinterpret_cast<bf16x8*>(&a_lds[r][c]) =
            *reinterpret_cast<const bf16x8*>(A + (size_t)grow * FD + c);
    }
    __syncthreads();

    const int mbase = (wv >> 1) * 32;   // wave's 32-row strip
    const int nbase = (wv & 1) * 64;    // wave's 64-col strip

    f32x4 acc[2][4];
#pragma unroll
    for (int m = 0; m < 2; ++m)
#pragma unroll
        for (int nf = 0; nf < 4; ++nf) acc[m][nf] = (f32x4){0.f, 0.f, 0.f, 0.f};

#pragma unroll
    for (int k0 = 0; k0 < 4; ++k0) {
        const int kk = k0 * 32 + g * 8;
        bf16x8 a0 = *reinterpret_cast<const bf16x8*>(&a_lds[mbase + l16][kk]);
        bf16x8 a1 = *reinterpret_cast<const bf16x8*>(&a_lds[mbase + 16 + l16][kk]);
#pragma unroll
        for (int nf = 0; nf < 4; ++nf) {
            bf16x8 b = *reinterpret_cast<const bf16x8*>(&w_lds[nbase + nf * 16 + l16][kk]);
            acc[0][nf] = __builtin_amdgcn_mfma_f32_16x16x32_bf16(a0, b, acc[0][nf], 0, 0, 0);
            acc[1][nf] = __builtin_amdgcn_mfma_f32_16x16x32_bf16(a1, b, acc[1][nf], 0, 0, 0);
        }
    }

    // epilogue: bias + relu
#pragma unroll
    for (int m = 0; m < 2; ++m) {
#pragma unroll
        for (int nf = 0; nf < 4; ++nf) {
            int col = nbase + nf * 16 + l16;
            float bc = bias[col];
#pragma unroll
            for (int r = 0; r < 4; ++r) {
                int row = row0 + mbase + 16 * m + g * 4 + r;
                if (row < NN) {
                    float v = fmaxf(acc[m][nf][r] + bc, 0.f);
                    if (F32OUT)
                        reinterpret_cast<float*>(outv)[(size_t)row * FD + col] = v;
                    else
                        reinterpret_cast<u16*>(outv)[(size_t)row * FD + col] = f2b(v);
                }
            }
        }
    }
}

extern "C" void kernel_launch(void* const* d_in, const int* in_sizes, int n_in,
                              void* d_out, int out_size, void* d_ws, size_t ws_size,
                              hipStream_t stream) {
    const float* x   = (const float*)d_in[0];
    const int*   ei  = (const int*)d_in[1];
    const int*   src = ei;
    const int*   dst = ei + NE;
    const float* W1a = (const float*)d_in[2];
    const float* b1a = (const float*)d_in[3];
    const float* W1b = (const float*)d_in[4];
    const float* b1b = (const float*)d_in[5];
    const float* W2a = (const float*)d_in[6];
    const float* b2a = (const float*)d_in[7];
    const float* W2b = (const float*)d_in[8];
    const float* b2b = (const float*)d_in[9];

    const size_t feat = (size_t)NN * FD;
    u16* xb = (u16*)d_ws;             // 12.8 MB (x, later h1)
    u16* zb = xb + feat;              // 12.8 MB
    u16* tb = zb + feat;              // 12.8 MB
    u16* wt = tb + feat;              // 4 * 128*128 bf16 = 128 KB
    int* row_off = (int*)(wt + 4 * FD * FD);  // NN+1
    int* cursor  = row_off + (NN + 1);
    int* deg     = cursor + NN;
    int* bsum    = deg + NN;          // NBLK
    int* boff    = bsum + 256;        // NBLK
    int* csr_src = boff + 256;        // NE

    const int eBlocks = (NE + 255) / 256;       // 3125
    const int cBlocks = (int)(feat / (256 * 8));// 3125
    const int gBlocks = (NN + 3) / 4;           // 12500
    const int mBlocks = (NN + 63) / 64;         // 782

    // converts
    convert_x_kernel<<<cBlocks, 256, 0, stream>>>(x, xb);
    convert_w_kernel<<<4, 256, 0, stream>>>(W1a, W1b, W2a, W2b, wt);

    // CSR build (once)
    hipMemsetAsync(deg, 0, NN * sizeof(int), stream);
    hist_kernel<<<eBlocks, 256, 0, stream>>>(dst, deg);
    scan_local_kernel<<<NBLK, 256, 0, stream>>>(deg, row_off, bsum);
    scan_block_kernel<<<1, 256, 0, stream>>>(bsum, boff);
    scan_add_kernel<<<NBLK, 256, 0, stream>>>(row_off, boff);
    hipMemcpyAsync(cursor, row_off, NN * sizeof(int), hipMemcpyDeviceToDevice, stream);
    fill_kernel<<<eBlocks, 256, 0, stream>>>(src, dst, cursor, csr_src);

    // conv1
    gather_sum_kernel<<<gBlocks, 256, 0, stream>>>(xb, csr_src, row_off, zb);
    gemm_mfma_kernel<false><<<mBlocks, 256, 0, stream>>>(zb, wt,             b1a, tb);
    gemm_mfma_kernel<false><<<mBlocks, 256, 0, stream>>>(tb, wt + 1 * FD*FD, b1b, xb);

    // conv2
    gather_sum_kernel<<<gBlocks, 256, 0, stream>>>(xb, csr_src, row_off, zb);
    gemm_mfma_kernel<false><<<mBlocks, 256, 0, stream>>>(zb, wt + 2 * FD*FD, b2a, tb);
    gemm_mfma_kernel<true ><<<mBlocks, 256, 0, stream>>>(tb, wt + 3 * FD*FD, b2b, (float*)d_out);
}